// Round 1
// baseline (358.301 us; speedup 1.0000x reference)
//
#include <hip/hip_runtime.h>

#define NN 20000
#define MM 5000
#define EE 320000
#define FD 128          // HEADS*OUT
#define KD 5000         // GEMM K == MM
#define NEG 0.2f

typedef __attribute__((ext_vector_type(4))) float f32x4;
typedef __attribute__((ext_vector_type(8))) short short8;

__device__ __forceinline__ unsigned int f2bf(float x){
  unsigned int u = __float_as_uint(x);
  return (u + 0x7fffu + ((u >> 16) & 1u)) >> 16;   // RNE
}
__device__ __forceinline__ unsigned int pack2(float lo, float hi){
  return f2bf(lo) | (f2bf(hi) << 16);
}

// ---------------- el[n][h] = sum_d feat[n][h*32+d]*attn_l[h][d] -------------
__global__ __launch_bounds__(256) void k_el(const float* __restrict__ feat,
                                            const float* __restrict__ attn_l,
                                            float* __restrict__ el){
  int t = threadIdx.x;
  int node = blockIdx.x*4 + (t>>6);
  int l = t & 63;
  float2 f = ((const float2*)feat)[(size_t)node*64 + l];
  float p = f.x*attn_l[2*l] + f.y*attn_l[2*l+1];
  p += __shfl_xor(p,1); p += __shfl_xor(p,2); p += __shfl_xor(p,4); p += __shfl_xor(p,8);
  if ((l&15)==0) el[node*4 + (l>>4)] = p;
}

// ---------------- e4[e] = leaky(el[src[e]] + em[e]) -------------------------
__global__ __launch_bounds__(256) void k_edge(const float* __restrict__ edge_feat,
                                              const float* __restrict__ attn_m,
                                              const float* __restrict__ el,
                                              const int* __restrict__ src,
                                              float4* __restrict__ e4){
  __shared__ float am[128];
  int t = threadIdx.x;
  if (t < 128) am[t] = attn_m[t];
  __syncthreads();
  int e = blockIdx.x*16 + (t>>4);
  int c = t & 15;
  float2 f = ((const float2*)edge_feat)[(size_t)e*16 + c];
  float p0 = f.x*am[0*32+2*c] + f.y*am[0*32+2*c+1];
  float p1 = f.x*am[1*32+2*c] + f.y*am[1*32+2*c+1];
  float p2 = f.x*am[2*32+2*c] + f.y*am[2*32+2*c+1];
  float p3 = f.x*am[3*32+2*c] + f.y*am[3*32+2*c+1];
  #pragma unroll
  for (int s=1; s<16; s<<=1){
    p0 += __shfl_xor(p0,s); p1 += __shfl_xor(p1,s);
    p2 += __shfl_xor(p2,s); p3 += __shfl_xor(p3,s);
  }
  if (c==0){
    float4 ev = ((const float4*)el)[src[e]];
    float4 r;
    float v;
    v = ev.x + p0; r.x = v > 0.f ? v : NEG*v;
    v = ev.y + p1; r.y = v > 0.f ? v : NEG*v;
    v = ev.z + p2; r.z = v > 0.f ? v : NEG*v;
    v = ev.w + p3; r.w = v > 0.f ? v : NEG*v;
    e4[e] = r;
  }
}

// ---------------- CSR build -------------------------------------------------
__global__ __launch_bounds__(256) void k_count(const int* __restrict__ dst,
                                               int* __restrict__ counts){
  int e = blockIdx.x*256 + threadIdx.x;
  if (e < EE) atomicAdd(&counts[dst[e]], 1);
}

__global__ __launch_bounds__(256) void k_scan(const int* __restrict__ counts,
                                              int* __restrict__ offsets){
  __shared__ int sc[256];
  int t = threadIdx.x;
  int loc[20];
  int sum = 0;
  #pragma unroll
  for (int j=0;j<20;j++){
    int idx = t*20 + j;
    int v = (idx < MM) ? counts[idx] : 0;
    loc[j] = sum; sum += v;
  }
  sc[t] = sum; __syncthreads();
  for (int s=1; s<256; s<<=1){
    int v = 0;
    if (t >= s) v = sc[t-s];
    __syncthreads();
    if (t >= s) sc[t] += v;
    __syncthreads();
  }
  int base = sc[t] - sum;   // exclusive over thread blocks
  #pragma unroll
  for (int j=0;j<20;j++){
    int idx = t*20 + j;
    if (idx < MM) offsets[idx] = base + loc[j];
  }
  if (t == 250) offsets[MM] = base;   // = total E
}

__global__ __launch_bounds__(256) void k_scatter(const int* __restrict__ dst,
                                                 const int* __restrict__ offsets,
                                                 int* __restrict__ cursor,
                                                 int* __restrict__ edge_ids){
  int e = blockIdx.x*256 + threadIdx.x;
  if (e < EE){
    int d = dst[e];
    int pos = atomicAdd(&cursor[d], 1);
    edge_ids[offsets[d] + pos] = e;
  }
}

// ------- per-dst softmax + aggregate; writes aggT[c][m] (bf16, transposed) --
__global__ __launch_bounds__(256) void k_agg(const float4* __restrict__ e4,
                                             const float* __restrict__ feat,
                                             const int* __restrict__ src,
                                             const int* __restrict__ edge_ids,
                                             const int* __restrict__ offsets,
                                             unsigned short* __restrict__ aggT){
  int m = blockIdx.x;
  int t = threadIdx.x;
  int beg = offsets[m], end = offsets[m+1];
  int cnt = end - beg;
  if (cnt == 0){
    if (t < FD) aggT[(size_t)t*KD + m] = 0;  // bf16 zero
    return;
  }
  __shared__ float wmax[4][4];
  __shared__ float smax[4];
  __shared__ float accs[4][FD];
  __shared__ float dens[4][4];
  // stage 1: per-head max
  float mx0=-1e30f, mx1=-1e30f, mx2=-1e30f, mx3=-1e30f;
  for (int i=t; i<cnt; i+=256){
    float4 ev = e4[edge_ids[beg+i]];
    mx0 = fmaxf(mx0, ev.x); mx1 = fmaxf(mx1, ev.y);
    mx2 = fmaxf(mx2, ev.z); mx3 = fmaxf(mx3, ev.w);
  }
  #pragma unroll
  for (int s=1; s<64; s<<=1){
    mx0 = fmaxf(mx0, __shfl_xor(mx0,s)); mx1 = fmaxf(mx1, __shfl_xor(mx1,s));
    mx2 = fmaxf(mx2, __shfl_xor(mx2,s)); mx3 = fmaxf(mx3, __shfl_xor(mx3,s));
  }
  if ((t&63)==0){ int w=t>>6; wmax[w][0]=mx0; wmax[w][1]=mx1; wmax[w][2]=mx2; wmax[w][3]=mx3; }
  __syncthreads();
  if (t < 4) smax[t] = fmaxf(fmaxf(wmax[0][t], wmax[1][t]), fmaxf(wmax[2][t], wmax[3][t]));
  __syncthreads();
  // stage 2: fused exp-sum + weighted accumulate (per-wave edge partition)
  int w = t>>6, l = t&63, h = l>>4;
  float mh = smax[h];
  float accx=0.f, accy=0.f, den=0.f;
  const float2* feat2 = (const float2*)feat;
  for (int i=w; i<cnt; i+=4){
    int eid = edge_ids[beg+i];
    float4 ev = e4[eid];
    float eh = (h==0)?ev.x:((h==1)?ev.y:((h==2)?ev.z:ev.w));
    float p = __expf(eh - mh);
    float2 f = feat2[(size_t)src[eid]*64 + l];
    accx += p*f.x; accy += p*f.y; den += p;
  }
  accs[w][2*l]   = accx;
  accs[w][2*l+1] = accy;
  if ((l&15)==0) dens[w][h] = den;
  __syncthreads();
  if (t < FD){
    float s = accs[0][t]+accs[1][t]+accs[2][t]+accs[3][t];
    float dn = dens[0][t>>5]+dens[1][t>>5]+dens[2][t>>5]+dens[3][t>>5];
    aggT[(size_t)t*KD + m] = (unsigned short)f2bf(s/dn);
  }
}

// ------- GEMM: out[N][128] = H[N][5000] * agg[5000][128], bf16 MFMA ---------
// BM=64, BN=128, BK=32; 512 threads = 8 waves, wave tile 16x64 (R=1,C=4)
__global__ __launch_bounds__(512) void k_gemm(const float* __restrict__ H,
                                              const unsigned short* __restrict__ aggT,
                                              float* __restrict__ out){
  __shared__ unsigned short As[64*32];    // [r][k] bf16, 64B rows
  __shared__ unsigned short Bs[128*32];   // [c][k] bf16 (B transposed)
  int t = threadIdx.x;
  int row0 = blockIdx.x * 64;
  int w = t>>6, l = t&63;
  int wrow = (w&3)*16, wcol = (w>>2)*64;

  f32x4 acc[4] = {{0,0,0,0},{0,0,0,0},{0,0,0,0},{0,0,0,0}};

  // staging assignments
  int ar = t>>3, aq = t&7;                 // A: row ar, k = 4*aq
  int bc = t>>2, bq = t&3;                 // B: col bc, k = 8*bq
  bool arow_ok = (row0 + ar) < NN;
  const float* Hp = H + (size_t)(arow_ok ? (row0+ar) : 0)*KD + 4*aq;
  const unsigned short* Bp = aggT + (size_t)bc*KD + 8*bq;

  for (int kt=0; kt<157; ++kt){
    int k0 = kt*32;
    // ---- stage A (f32 -> bf16) ----
    float4 hv = make_float4(0.f,0.f,0.f,0.f);
    if (arow_ok && (k0 + 4*aq) < KD) hv = *(const float4*)(Hp + k0);
    uint2 ap; ap.x = pack2(hv.x, hv.y); ap.y = pack2(hv.z, hv.w);
    *(uint2*)&As[ar*32 + 4*aq] = ap;
    // ---- stage B (bf16 copy, already transposed in global) ----
    uint4 bv = make_uint4(0u,0u,0u,0u);
    if ((k0 + 8*bq) < KD) bv = *(const uint4*)(Bp + k0);
    *(uint4*)&Bs[bc*32 + 8*bq] = bv;
    __syncthreads();
    // ---- compute ----
    short8 a = *(const short8*)&As[(wrow + (l&15))*32 + 8*(l>>4)];
    #pragma unroll
    for (int j=0;j<4;j++){
      short8 b = *(const short8*)&Bs[(wcol + j*16 + (l&15))*32 + 8*(l>>4)];
      acc[j] = __builtin_amdgcn_mfma_f32_16x16x32_bf16(a, b, acc[j], 0, 0, 0);
    }
    __syncthreads();
  }
  // ---- epilogue: D row=(l>>4)*4+p, col=l&15 (m89-verified layout) ----
  int rbase = row0 + wrow + (l>>4)*4;
  int cbase = wcol + (l&15);
  #pragma unroll
  for (int j=0;j<4;j++){
    #pragma unroll
    for (int p=0;p<4;p++){
      int r = rbase + p;
      if (r < NN) out[(size_t)r*FD + cbase + j*16] = acc[j][p];
    }
  }
}

extern "C" void kernel_launch(void* const* d_in, const int* in_sizes, int n_in,
                              void* d_out, int out_size, void* d_ws, size_t ws_size,
                              hipStream_t stream) {
  const float* feat      = (const float*)d_in[0];
  const float* edge_feat = (const float*)d_in[1];
  const float* H         = (const float*)d_in[2];
  const float* attn_l    = (const float*)d_in[3];
  const float* attn_m    = (const float*)d_in[4];
  const int*   src       = (const int*)d_in[5];
  const int*   dst       = (const int*)d_in[6];
  float* out = (float*)d_out;

  char* w = (char*)d_ws;
  float*          el       = (float*)(w + 0);            //   320000 B
  float4*         e4       = (float4*)(w + 320000);      //  5120000 B
  int*            counts   = (int*)(w + 5440000);        //    20480 B
  int*            cursor   = (int*)(w + 5460480);        //    20480 B
  int*            offsets  = (int*)(w + 5480960);        //    20480 B
  int*            edge_ids = (int*)(w + 5501440);        //  1280000 B
  unsigned short* aggT     = (unsigned short*)(w + 6781440); // 1280000 B
  // total 8061440 B

  hipMemsetAsync(counts, 0, 2*20480, stream);   // counts + cursor (adjacent)

  k_el     <<<NN/4,   256, 0, stream>>>(feat, attn_l, el);
  k_edge   <<<EE/16,  256, 0, stream>>>(edge_feat, attn_m, el, src, e4);
  k_count  <<<EE/256, 256, 0, stream>>>(dst, counts);
  k_scan   <<<1,      256, 0, stream>>>(counts, offsets);
  k_scatter<<<EE/256, 256, 0, stream>>>(dst, offsets, cursor, edge_ids);
  k_agg    <<<MM,     256, 0, stream>>>(e4, feat, src, edge_ids, offsets, aggT);
  k_gemm   <<<(NN+63)/64, 512, 0, stream>>>(H, aggT, out);
}

// Round 2
// 295.179 us; speedup vs baseline: 1.2138x; 1.2138x over previous
//
#include <hip/hip_runtime.h>

#define NN 20000
#define MM 5000
#define EE 320000
#define FD 128          // HEADS*OUT
#define KD 5000         // GEMM K == MM
#define K2 5056         // padded K (79 * 64)
#define NEG 0.2f

typedef __attribute__((ext_vector_type(4))) float f32x4;
typedef __attribute__((ext_vector_type(8))) short short8;

__device__ __forceinline__ unsigned int f2bf(float x){
  unsigned int u = __float_as_uint(x);
  return (u + 0x7fffu + ((u >> 16) & 1u)) >> 16;   // RNE
}
__device__ __forceinline__ unsigned int cvtpk(float lo, float hi){
  unsigned int r;
  asm volatile("v_cvt_pk_bf16_f32 %0, %1, %2" : "=v"(r) : "v"(lo), "v"(hi));
  return r;
}

// ---------------- el[n][h] = sum_d feat[n][h*32+d]*attn_l[h][d] -------------
__global__ __launch_bounds__(256) void k_el(const float* __restrict__ feat,
                                            const float* __restrict__ attn_l,
                                            float* __restrict__ el){
  int t = threadIdx.x;
  int node = blockIdx.x*4 + (t>>6);
  int l = t & 63;
  float2 f = ((const float2*)feat)[(size_t)node*64 + l];
  float p = f.x*attn_l[2*l] + f.y*attn_l[2*l+1];
  p += __shfl_xor(p,1); p += __shfl_xor(p,2); p += __shfl_xor(p,4); p += __shfl_xor(p,8);
  if ((l&15)==0) el[node*4 + (l>>4)] = p;
}

// ---------------- e4[e] = leaky(el[src[e]] + em[e]) -------------------------
__global__ __launch_bounds__(256) void k_edge(const float* __restrict__ edge_feat,
                                              const float* __restrict__ attn_m,
                                              const float* __restrict__ el,
                                              const int* __restrict__ src,
                                              float4* __restrict__ e4){
  __shared__ float am[128];
  int t = threadIdx.x;
  if (t < 128) am[t] = attn_m[t];
  __syncthreads();
  int e = blockIdx.x*16 + (t>>4);
  int c = t & 15;
  float2 f = ((const float2*)edge_feat)[(size_t)e*16 + c];
  float p0 = f.x*am[0*32+2*c] + f.y*am[0*32+2*c+1];
  float p1 = f.x*am[1*32+2*c] + f.y*am[1*32+2*c+1];
  float p2 = f.x*am[2*32+2*c] + f.y*am[2*32+2*c+1];
  float p3 = f.x*am[3*32+2*c] + f.y*am[3*32+2*c+1];
  #pragma unroll
  for (int s=1; s<16; s<<=1){
    p0 += __shfl_xor(p0,s); p1 += __shfl_xor(p1,s);
    p2 += __shfl_xor(p2,s); p3 += __shfl_xor(p3,s);
  }
  if (c==0){
    float4 ev = ((const float4*)el)[src[e]];
    float4 r;
    float v;
    v = ev.x + p0; r.x = v > 0.f ? v : NEG*v;
    v = ev.y + p1; r.y = v > 0.f ? v : NEG*v;
    v = ev.z + p2; r.z = v > 0.f ? v : NEG*v;
    v = ev.w + p3; r.w = v > 0.f ? v : NEG*v;
    e4[e] = r;
  }
}

// ---------------- CSR build -------------------------------------------------
__global__ __launch_bounds__(256) void k_count(const int* __restrict__ dst,
                                               int* __restrict__ counts){
  int e = blockIdx.x*256 + threadIdx.x;
  if (e < EE) atomicAdd(&counts[dst[e]], 1);
}

__global__ __launch_bounds__(256) void k_scan(const int* __restrict__ counts,
                                              int* __restrict__ offsets){
  __shared__ int sc[256];
  int t = threadIdx.x;
  int loc[20];
  int sum = 0;
  #pragma unroll
  for (int j=0;j<20;j++){
    int idx = t*20 + j;
    int v = (idx < MM) ? counts[idx] : 0;
    loc[j] = sum; sum += v;
  }
  sc[t] = sum; __syncthreads();
  for (int s=1; s<256; s<<=1){
    int v = 0;
    if (t >= s) v = sc[t-s];
    __syncthreads();
    if (t >= s) sc[t] += v;
    __syncthreads();
  }
  int base = sc[t] - sum;   // exclusive over thread blocks
  #pragma unroll
  for (int j=0;j<20;j++){
    int idx = t*20 + j;
    if (idx < MM) offsets[idx] = base + loc[j];
  }
  if (t == 250) offsets[MM] = base;   // = total E
}

__global__ __launch_bounds__(256) void k_scatter(const int* __restrict__ dst,
                                                 const int* __restrict__ offsets,
                                                 int* __restrict__ cursor,
                                                 int* __restrict__ edge_ids){
  int e = blockIdx.x*256 + threadIdx.x;
  if (e < EE){
    int d = dst[e];
    int pos = atomicAdd(&cursor[d], 1);
    edge_ids[offsets[d] + pos] = e;
  }
}

// ------- per-dst softmax + aggregate; writes aggT[c][k] (bf16, K2-padded) ---
__global__ __launch_bounds__(256) void k_agg(const float4* __restrict__ e4,
                                             const float* __restrict__ feat,
                                             const int* __restrict__ src,
                                             const int* __restrict__ edge_ids,
                                             const int* __restrict__ offsets,
                                             unsigned short* __restrict__ aggT){
  int m = blockIdx.x;
  int t = threadIdx.x;
  // zero the K-pad region (k in [5000, 5056)) once per call
  if (m < (K2 - KD) && t < FD) aggT[(size_t)t*K2 + KD + m] = 0;
  int beg = offsets[m], end = offsets[m+1];
  int cnt = end - beg;
  if (cnt == 0){
    if (t < FD) aggT[(size_t)t*K2 + m] = 0;  // bf16 zero
    return;
  }
  __shared__ float wmax[4][4];
  __shared__ float smax[4];
  __shared__ float accs[4][FD];
  __shared__ float dens[4][4];
  // stage 1: per-head max
  float mx0=-1e30f, mx1=-1e30f, mx2=-1e30f, mx3=-1e30f;
  for (int i=t; i<cnt; i+=256){
    float4 ev = e4[edge_ids[beg+i]];
    mx0 = fmaxf(mx0, ev.x); mx1 = fmaxf(mx1, ev.y);
    mx2 = fmaxf(mx2, ev.z); mx3 = fmaxf(mx3, ev.w);
  }
  #pragma unroll
  for (int s=1; s<64; s<<=1){
    mx0 = fmaxf(mx0, __shfl_xor(mx0,s)); mx1 = fmaxf(mx1, __shfl_xor(mx1,s));
    mx2 = fmaxf(mx2, __shfl_xor(mx2,s)); mx3 = fmaxf(mx3, __shfl_xor(mx3,s));
  }
  if ((t&63)==0){ int w=t>>6; wmax[w][0]=mx0; wmax[w][1]=mx1; wmax[w][2]=mx2; wmax[w][3]=mx3; }
  __syncthreads();
  if (t < 4) smax[t] = fmaxf(fmaxf(wmax[0][t], wmax[1][t]), fmaxf(wmax[2][t], wmax[3][t]));
  __syncthreads();
  // stage 2: fused exp-sum + weighted accumulate (per-wave edge partition)
  int w = t>>6, l = t&63, h = l>>4;
  float mh = smax[h];
  float accx=0.f, accy=0.f, den=0.f;
  const float2* feat2 = (const float2*)feat;
  for (int i=w; i<cnt; i+=4){
    int eid = edge_ids[beg+i];
    float4 ev = e4[eid];
    float eh = (h==0)?ev.x:((h==1)?ev.y:((h==2)?ev.z:ev.w));
    float p = __expf(eh - mh);
    float2 f = feat2[(size_t)src[eid]*64 + l];
    accx += p*f.x; accy += p*f.y; den += p;
  }
  accs[w][2*l]   = accx;
  accs[w][2*l+1] = accy;
  if ((l&15)==0) dens[w][h] = den;
  __syncthreads();
  if (t < FD){
    float s = accs[0][t]+accs[1][t]+accs[2][t]+accs[3][t];
    float dn = dens[0][t>>5]+dens[1][t>>5]+dens[2][t>>5]+dens[3][t>>5];
    aggT[(size_t)t*K2 + m] = (unsigned short)f2bf(s/dn);
  }
}

// ------- GEMM: out[N][128] = H[N][5000] * agg[5000][128], bf16 MFMA ---------
// BM=32, BN=128, BK=64; 512 threads = 8 waves (2 row x 4 col), wave tile 16x32
// LDS XOR-swizzled (byte ^= (row&7)<<4) -> conflict-free ds_read_b128
// reg-staged pipeline: issue next tile loads after barrier, write after compute
__global__ __launch_bounds__(512) void k_gemm(const float* __restrict__ H,
                                              const unsigned short* __restrict__ aggT,
                                              float* __restrict__ out){
  __shared__ unsigned short As[32*64];    // [row][k] bf16, 128B rows, swizzled
  __shared__ unsigned short Bs[128*64];   // [col][k] bf16, 128B rows, swizzled
  int t = threadIdx.x;
  int row0 = blockIdx.x * 32;

  // staging assignments
  int arow = t>>4, akq = t&15;             // A: row, k-quad (4 f32 = 16B)
  int bcol = t>>2, bkq = t&3;              // B: col, k-16 chunk (16 bf16 = 32B)
  const float* Ap = H + (size_t)(row0+arow)*KD + akq*4;
  const unsigned short* Bp = aggT + (size_t)bcol*K2 + bkq*16;
  char* AsW  = (char*)As + arow*128 + ((akq*8) ^ ((arow&7)<<4));
  char* BsW0 = (char*)Bs + bcol*128 + ((bkq*32)      ^ ((bcol&7)<<4));
  char* BsW1 = (char*)Bs + bcol*128 + ((bkq*32 + 16) ^ ((bcol&7)<<4));

  // fragment read addressing
  int w = t>>6, l = t&63;
  int wr = (w>>2)*16, wc = (w&3)*32;
  int rl = l&15, ks = l>>4;
  int arow2 = wr + rl;
  const char* Af  = (const char*)As + arow2*128;
  int aswz = (arow2&7)<<4;
  int c0 = wc + rl;
  const char* Bf0 = (const char*)Bs + c0*128;
  const char* Bf1 = (const char*)Bs + (c0+16)*128;
  int bswz = (c0&7)<<4;                    // (c0+16)&7 == c0&7

  f32x4 acc0 = {0,0,0,0}, acc1 = {0,0,0,0};

  float4 hv; uint4 bv0, bv1;
  // prologue: tile 0
  {
    hv = (akq*4 < KD) ? *(const float4*)(Ap) : make_float4(0.f,0.f,0.f,0.f);
    bv0 = *(const uint4*)(Bp);
    bv1 = *(const uint4*)(Bp + 8);
    uint2 ap; ap.x = cvtpk(hv.x, hv.y); ap.y = cvtpk(hv.z, hv.w);
    *(uint2*)AsW = ap;
    *(uint4*)BsW0 = bv0;
    *(uint4*)BsW1 = bv1;
  }

  for (int kt=0; kt<79; ++kt){
    __syncthreads();
    if (kt < 78){
      int k = (kt+1)*64 + akq*4;
      hv = (k < KD) ? *(const float4*)(Ap + (kt+1)*64) : make_float4(0.f,0.f,0.f,0.f);
      bv0 = *(const uint4*)(Bp + (kt+1)*64);
      bv1 = *(const uint4*)(Bp + (kt+1)*64 + 8);
    }
    // compute current tile from LDS
    short8 a0  = *(const short8*)(Af  + ((     ks*16) ^ aswz));
    short8 a1  = *(const short8*)(Af  + ((64 + ks*16) ^ aswz));
    short8 b00 = *(const short8*)(Bf0 + ((     ks*16) ^ bswz));
    short8 b01 = *(const short8*)(Bf0 + ((64 + ks*16) ^ bswz));
    short8 b10 = *(const short8*)(Bf1 + ((     ks*16) ^ bswz));
    short8 b11 = *(const short8*)(Bf1 + ((64 + ks*16) ^ bswz));
    acc0 = __builtin_amdgcn_mfma_f32_16x16x32_bf16(a0, b00, acc0, 0, 0, 0);
    acc1 = __builtin_amdgcn_mfma_f32_16x16x32_bf16(a0, b10, acc1, 0, 0, 0);
    acc0 = __builtin_amdgcn_mfma_f32_16x16x32_bf16(a1, b01, acc0, 0, 0, 0);
    acc1 = __builtin_amdgcn_mfma_f32_16x16x32_bf16(a1, b11, acc1, 0, 0, 0);
    __syncthreads();
    if (kt < 78){
      uint2 ap; ap.x = cvtpk(hv.x, hv.y); ap.y = cvtpk(hv.z, hv.w);
      *(uint2*)AsW = ap;
      *(uint4*)BsW0 = bv0;
      *(uint4*)BsW1 = bv1;
    }
  }

  // epilogue: D row=(l>>4)*4+p, col=l&15 (m89-verified layout)
  int orow = row0 + wr + ks*4;
  #pragma unroll
  for (int p=0;p<4;p++){
    out[(size_t)(orow+p)*FD + wc + rl]      = acc0[p];
    out[(size_t)(orow+p)*FD + wc + 16 + rl] = acc1[p];
  }
}

extern "C" void kernel_launch(void* const* d_in, const int* in_sizes, int n_in,
                              void* d_out, int out_size, void* d_ws, size_t ws_size,
                              hipStream_t stream) {
  const float* feat      = (const float*)d_in[0];
  const float* edge_feat = (const float*)d_in[1];
  const float* H         = (const float*)d_in[2];
  const float* attn_l    = (const float*)d_in[3];
  const float* attn_m    = (const float*)d_in[4];
  const int*   src       = (const int*)d_in[5];
  const int*   dst       = (const int*)d_in[6];
  float* out = (float*)d_out;

  char* w = (char*)d_ws;
  // el ([0,320000)) and aggT ([0,1294336)) have disjoint lifetimes -> overlap
  float*          el       = (float*)(w + 0);                //  320000 B (dead after k_edge)
  unsigned short* aggT     = (unsigned short*)(w + 0);       // 1294336 B (live from k_agg)
  float4*         e4       = (float4*)(w + 1294336);         // 5120000 B
  int*            counts   = (int*)(w + 6414336);            //   20480 B
  int*            cursor   = (int*)(w + 6434816);            //   20480 B
  int*            offsets  = (int*)(w + 6455296);            //   20480 B
  int*            edge_ids = (int*)(w + 6475776);            // 1280000 B
  // total 7755776 B

  hipMemsetAsync(counts, 0, 2*20480, stream);   // counts + cursor (adjacent)

  k_el     <<<NN/4,   256, 0, stream>>>(feat, attn_l, el);
  k_edge   <<<EE/16,  256, 0, stream>>>(edge_feat, attn_m, el, src, e4);
  k_count  <<<EE/256, 256, 0, stream>>>(dst, counts);
  k_scan   <<<1,      256, 0, stream>>>(counts, offsets);
  k_scatter<<<EE/256, 256, 0, stream>>>(dst, offsets, cursor, edge_ids);
  k_agg    <<<MM,     256, 0, stream>>>(e4, feat, src, edge_ids, offsets, aggT);
  k_gemm   <<<NN/32,  512, 0, stream>>>(H, aggT, out);
}

// Round 3
// 279.823 us; speedup vs baseline: 1.2805x; 1.0549x over previous
//
#include <hip/hip_runtime.h>

#define NN 20000
#define MM 5000
#define EE 320000
#define FD 128          // HEADS*OUT
#define KD 5000         // GEMM K == MM
#define K2 5056         // padded K (79 * 64)
#define NEG 0.2f
#define BUFB 20480      // one LDS buffer: A(4KB) + B(16KB)
#define BOFF 4096       // B region offset inside a buffer

typedef __attribute__((ext_vector_type(4))) float f32x4;
typedef __attribute__((ext_vector_type(8))) short short8;

__device__ __forceinline__ unsigned int f2bf(float x){
  unsigned int u = __float_as_uint(x);
  return (u + 0x7fffu + ((u >> 16) & 1u)) >> 16;   // RNE
}
__device__ __forceinline__ unsigned int cvtpk(float lo, float hi){
  unsigned int r;
  asm volatile("v_cvt_pk_bf16_f32 %0, %1, %2" : "=v"(r) : "v"(lo), "v"(hi));
  return r;
}

// ---------------- el[n][h] = sum_d feat[n][h*32+d]*attn_l[h][d] -------------
__global__ __launch_bounds__(256) void k_el(const float* __restrict__ feat,
                                            const float* __restrict__ attn_l,
                                            float* __restrict__ el){
  int t = threadIdx.x;
  int node = blockIdx.x*4 + (t>>6);
  int l = t & 63;
  float2 f = ((const float2*)feat)[(size_t)node*64 + l];
  float p = f.x*attn_l[2*l] + f.y*attn_l[2*l+1];
  p += __shfl_xor(p,1); p += __shfl_xor(p,2); p += __shfl_xor(p,4); p += __shfl_xor(p,8);
  if ((l&15)==0) el[node*4 + (l>>4)] = p;
}

// ------ e4[e] = leaky(el[src[e]] + em[e]); also histogram dst (fused) -------
__global__ __launch_bounds__(256) void k_edge(const float* __restrict__ edge_feat,
                                              const float* __restrict__ attn_m,
                                              const float* __restrict__ el,
                                              const int* __restrict__ src,
                                              const int* __restrict__ dst,
                                              int* __restrict__ counts,
                                              float4* __restrict__ e4){
  __shared__ float am[128];
  int t = threadIdx.x;
  if (t < 128) am[t] = attn_m[t];
  __syncthreads();
  int e = blockIdx.x*16 + (t>>4);
  int c = t & 15;
  float2 f = ((const float2*)edge_feat)[(size_t)e*16 + c];
  float p0 = f.x*am[0*32+2*c] + f.y*am[0*32+2*c+1];
  float p1 = f.x*am[1*32+2*c] + f.y*am[1*32+2*c+1];
  float p2 = f.x*am[2*32+2*c] + f.y*am[2*32+2*c+1];
  float p3 = f.x*am[3*32+2*c] + f.y*am[3*32+2*c+1];
  #pragma unroll
  for (int s=1; s<16; s<<=1){
    p0 += __shfl_xor(p0,s); p1 += __shfl_xor(p1,s);
    p2 += __shfl_xor(p2,s); p3 += __shfl_xor(p3,s);
  }
  if (c==0){
    float4 ev = ((const float4*)el)[src[e]];
    float4 r;
    float v;
    v = ev.x + p0; r.x = v > 0.f ? v : NEG*v;
    v = ev.y + p1; r.y = v > 0.f ? v : NEG*v;
    v = ev.z + p2; r.z = v > 0.f ? v : NEG*v;
    v = ev.w + p3; r.w = v > 0.f ? v : NEG*v;
    e4[e] = r;
    atomicAdd(&counts[dst[e]], 1);
  }
}

// ---------------- CSR build -------------------------------------------------
__global__ __launch_bounds__(256) void k_scan(const int* __restrict__ counts,
                                              int* __restrict__ offsets){
  __shared__ int sc[256];
  int t = threadIdx.x;
  int loc[20];
  int sum = 0;
  #pragma unroll
  for (int j=0;j<20;j++){
    int idx = t*20 + j;
    int v = (idx < MM) ? counts[idx] : 0;
    loc[j] = sum; sum += v;
  }
  sc[t] = sum; __syncthreads();
  for (int s=1; s<256; s<<=1){
    int v = 0;
    if (t >= s) v = sc[t-s];
    __syncthreads();
    if (t >= s) sc[t] += v;
    __syncthreads();
  }
  int base = sc[t] - sum;   // exclusive over thread blocks
  #pragma unroll
  for (int j=0;j<20;j++){
    int idx = t*20 + j;
    if (idx < MM) offsets[idx] = base + loc[j];
  }
  if (t == 250) offsets[MM] = base;   // = total E
}

__global__ __launch_bounds__(256) void k_scatter(const int* __restrict__ dst,
                                                 const int* __restrict__ offsets,
                                                 int* __restrict__ cursor,
                                                 int* __restrict__ edge_ids){
  int e = blockIdx.x*256 + threadIdx.x;
  if (e < EE){
    int d = dst[e];
    int pos = atomicAdd(&cursor[d], 1);
    edge_ids[offsets[d] + pos] = e;
  }
}

// ------- per-dst softmax + aggregate; writes aggT[c][k] (bf16, K2-padded) ---
__global__ __launch_bounds__(256) void k_agg(const float4* __restrict__ e4,
                                             const float* __restrict__ feat,
                                             const int* __restrict__ src,
                                             const int* __restrict__ edge_ids,
                                             const int* __restrict__ offsets,
                                             unsigned short* __restrict__ aggT){
  int m = blockIdx.x;
  int t = threadIdx.x;
  // zero the K-pad region (k in [5000, 5056)) once per call
  if (m < (K2 - KD) && t < FD) aggT[(size_t)t*K2 + KD + m] = 0;
  int beg = offsets[m], end = offsets[m+1];
  int cnt = end - beg;
  if (cnt == 0){
    if (t < FD) aggT[(size_t)t*K2 + m] = 0;  // bf16 zero
    return;
  }
  __shared__ float wmax[4][4];
  __shared__ float smax[4];
  __shared__ float accs[4][FD];
  __shared__ float dens[4][4];
  // stage 1: per-head max
  float mx0=-1e30f, mx1=-1e30f, mx2=-1e30f, mx3=-1e30f;
  for (int i=t; i<cnt; i+=256){
    float4 ev = e4[edge_ids[beg+i]];
    mx0 = fmaxf(mx0, ev.x); mx1 = fmaxf(mx1, ev.y);
    mx2 = fmaxf(mx2, ev.z); mx3 = fmaxf(mx3, ev.w);
  }
  #pragma unroll
  for (int s=1; s<64; s<<=1){
    mx0 = fmaxf(mx0, __shfl_xor(mx0,s)); mx1 = fmaxf(mx1, __shfl_xor(mx1,s));
    mx2 = fmaxf(mx2, __shfl_xor(mx2,s)); mx3 = fmaxf(mx3, __shfl_xor(mx3,s));
  }
  if ((t&63)==0){ int w=t>>6; wmax[w][0]=mx0; wmax[w][1]=mx1; wmax[w][2]=mx2; wmax[w][3]=mx3; }
  __syncthreads();
  if (t < 4) smax[t] = fmaxf(fmaxf(wmax[0][t], wmax[1][t]), fmaxf(wmax[2][t], wmax[3][t]));
  __syncthreads();
  // stage 2: fused exp-sum + weighted accumulate (per-wave edge partition)
  int w = t>>6, l = t&63, h = l>>4;
  float mh = smax[h];
  float accx=0.f, accy=0.f, den=0.f;
  const float2* feat2 = (const float2*)feat;
  for (int i=w; i<cnt; i+=4){
    int eid = edge_ids[beg+i];
    float4 ev = e4[eid];
    float eh = (h==0)?ev.x:((h==1)?ev.y:((h==2)?ev.z:ev.w));
    float p = __expf(eh - mh);
    float2 f = feat2[(size_t)src[eid]*64 + l];
    accx += p*f.x; accy += p*f.y; den += p;
  }
  accs[w][2*l]   = accx;
  accs[w][2*l+1] = accy;
  if ((l&15)==0) dens[w][h] = den;
  __syncthreads();
  if (t < FD){
    float s = accs[0][t]+accs[1][t]+accs[2][t]+accs[3][t];
    float dn = dens[0][t>>5]+dens[1][t>>5]+dens[2][t>>5]+dens[3][t>>5];
    aggT[(size_t)t*K2 + m] = (unsigned short)f2bf(s/dn);
  }
}

// ------- GEMM: out[N][128] = H[N][5000] * agg[5000][128], bf16 MFMA ---------
// BM=32, BN=128, BK=64; 512 threads = 8 waves (2 row x 4 col), wave tile 16x32
// Depth-2 prefetch, double-buffered XOR-swizzled LDS, 1 barrier per K-step.
// iter t: issue loads(tile t+2) -> set[t&1]; compute buf[t&1];
//         write set[(t+1)&1] -> buf[(t+1)&1]   (counted vmcnt by compiler)
__global__ __launch_bounds__(512) void k_gemm(const float* __restrict__ H,
                                              const unsigned short* __restrict__ aggT,
                                              float* __restrict__ out){
  __shared__ char lds[2*BUFB];
  int t = threadIdx.x;
  int row0 = blockIdx.x * 32;

  // staging assignments
  int arow = t>>4, akq = t&15;             // A: row, k-quad (4 f32 = 16B)
  int bcol = t>>2, bkq = t&3;              // B: col, 16-bf16 chunk (32B)
  const float* Ap = H + (size_t)(row0+arow)*KD + akq*4;
  const unsigned short* Bp = aggT + (size_t)bcol*K2 + bkq*16;
  int awoff  = arow*128 + ((akq*8) ^ ((arow&7)<<4));
  int bwoff0 = BOFF + bcol*128 + ((bkq*32)      ^ ((bcol&7)<<4));
  int bwoff1 = BOFF + bcol*128 + ((bkq*32 + 16) ^ ((bcol&7)<<4));

  // fragment read addressing
  int w = t>>6, l = t&63;
  int wr = (w>>2)*16, wc = (w&3)*32;
  int rl = l&15, ks = l>>4;
  int aro  = (wr+rl)*128;  int aswz = ((wr+rl)&7)<<4;
  int c0 = wc + rl;
  int bro0 = BOFF + c0*128, bro1 = BOFF + (c0+16)*128;
  int bswz = (c0&7)<<4;                    // (c0+16)&7 == c0&7

  f32x4 acc0 = {0,0,0,0}, acc1 = {0,0,0,0};

  float4 ha; uint4 b0a, b1a;   // set S0 (even tiles)
  float4 hb; uint4 b0b, b1b;   // set S1 (odd tiles)

  // prologue: issue tile0 -> S0, tile1 -> S1, write S0 -> buf0
  ha  = *(const float4*)(Ap);
  b0a = *(const uint4*)(Bp);
  b1a = *(const uint4*)(Bp + 8);
  hb  = *(const float4*)(Ap + 64);
  b0b = *(const uint4*)(Bp + 64);
  b1b = *(const uint4*)(Bp + 64 + 8);
  { uint2 ap; ap.x = cvtpk(ha.x, ha.y); ap.y = cvtpk(ha.z, ha.w);
    *(uint2*)(lds + awoff) = ap;
    *(uint4*)(lds + bwoff0) = b0a;
    *(uint4*)(lds + bwoff1) = b1a; }

#define GBODY(T, P, HI, B0I, B1I, HW, B0W, B1W)                               \
  { __syncthreads();                                                          \
    if ((T) < 77){                                                            \
      int ti = (T) + 2; int kk = ti*64 + akq*4;                               \
      HI  = (kk < KD) ? *(const float4*)(Ap + ti*64)                          \
                      : make_float4(0.f,0.f,0.f,0.f);                         \
      B0I = *(const uint4*)(Bp + ti*64);                                      \
      B1I = *(const uint4*)(Bp + ti*64 + 8);                                  \
    }                                                                         \
    { const char* R_ = lds + (P)*BUFB;                                        \
      short8 a0  = *(const short8*)(R_ + aro  + ((     ks*16) ^ aswz));       \
      short8 a1  = *(const short8*)(R_ + aro  + ((64 + ks*16) ^ aswz));       \
      short8 b00 = *(const short8*)(R_ + bro0 + ((     ks*16) ^ bswz));       \
      short8 b01 = *(const short8*)(R_ + bro0 + ((64 + ks*16) ^ bswz));       \
      short8 b10 = *(const short8*)(R_ + bro1 + ((     ks*16) ^ bswz));       \
      short8 b11 = *(const short8*)(R_ + bro1 + ((64 + ks*16) ^ bswz));       \
      acc0 = __builtin_amdgcn_mfma_f32_16x16x32_bf16(a0, b00, acc0, 0, 0, 0); \
      acc1 = __builtin_amdgcn_mfma_f32_16x16x32_bf16(a0, b10, acc1, 0, 0, 0); \
      acc0 = __builtin_amdgcn_mfma_f32_16x16x32_bf16(a1, b01, acc0, 0, 0, 0); \
      acc1 = __builtin_amdgcn_mfma_f32_16x16x32_bf16(a1, b11, acc1, 0, 0, 0); \
    }                                                                         \
    if ((T) < 78){                                                            \
      char* W_ = lds + (1-(P))*BUFB;                                          \
      uint2 ap; ap.x = cvtpk(HW.x, HW.y); ap.y = cvtpk(HW.z, HW.w);           \
      *(uint2*)(W_ + awoff)  = ap;                                            \
      *(uint4*)(W_ + bwoff0) = B0W;                                           \
      *(uint4*)(W_ + bwoff1) = B1W;                                           \
    } }

  for (int tp = 0; tp < 79; tp += 2){
    GBODY(tp,   0, ha, b0a, b1a, hb, b0b, b1b)
    if (tp + 1 < 79){
      GBODY(tp+1, 1, hb, b0b, b1b, ha, b0a, b1a)
    }
  }
#undef GBODY

  // epilogue: D row=(l>>4)*4+p, col=l&15 (m89-verified layout)
  int orow = row0 + wr + ks*4;
  #pragma unroll
  for (int p=0;p<4;p++){
    out[(size_t)(orow+p)*FD + wc + rl]      = acc0[p];
    out[(size_t)(orow+p)*FD + wc + 16 + rl] = acc1[p];
  }
}

extern "C" void kernel_launch(void* const* d_in, const int* in_sizes, int n_in,
                              void* d_out, int out_size, void* d_ws, size_t ws_size,
                              hipStream_t stream) {
  const float* feat      = (const float*)d_in[0];
  const float* edge_feat = (const float*)d_in[1];
  const float* H         = (const float*)d_in[2];
  const float* attn_l    = (const float*)d_in[3];
  const float* attn_m    = (const float*)d_in[4];
  const int*   src       = (const int*)d_in[5];
  const int*   dst       = (const int*)d_in[6];
  float* out = (float*)d_out;

  char* w = (char*)d_ws;
  // el ([0,320000)) and aggT ([0,1294336)) have disjoint lifetimes -> overlap
  float*          el       = (float*)(w + 0);                //  320000 B (dead after k_edge)
  unsigned short* aggT     = (unsigned short*)(w + 0);       // 1294336 B (live from k_agg)
  float4*         e4       = (float4*)(w + 1294336);         // 5120000 B
  int*            counts   = (int*)(w + 6414336);            //   20480 B
  int*            cursor   = (int*)(w + 6434816);            //   20480 B
  int*            offsets  = (int*)(w + 6455296);            //   20480 B
  int*            edge_ids = (int*)(w + 6475776);            // 1280000 B
  // total 7755776 B

  hipMemsetAsync(counts, 0, 2*20480, stream);   // counts + cursor (adjacent)

  k_el     <<<NN/4,   256, 0, stream>>>(feat, attn_l, el);
  k_edge   <<<EE/16,  256, 0, stream>>>(edge_feat, attn_m, el, src, dst, counts, e4);
  k_scan   <<<1,      256, 0, stream>>>(counts, offsets);
  k_scatter<<<EE/256, 256, 0, stream>>>(dst, offsets, cursor, edge_ids);
  k_agg    <<<MM,     256, 0, stream>>>(e4, feat, src, edge_ids, offsets, aggT);
  k_gemm   <<<NN/32,  512, 0, stream>>>(H, aggT, out);
}